// Round 9
// baseline (212.028 us; speedup 1.0000x reference)
//
#include <hip/hip_runtime.h>
#include <hip/hip_bf16.h>

#define B_ 4
#define S_ 1024
#define D_ 256
#define H_ 8
#define LRELU_ALPHA 0.2f
#define MAXDEG 128

typedef __attribute__((ext_vector_type(8))) short short8;
typedef __attribute__((ext_vector_type(4))) float floatx4;

__device__ __forceinline__ float bf2f(unsigned short u) {
    union { unsigned int i; float f; } c; c.i = ((unsigned int)u) << 16; return c.f;
}
__device__ __forceinline__ unsigned short f2bf(float f) {
    union { float f; unsigned int u; } c; c.f = f;
    unsigned int r = (c.u + 0x7FFF + ((c.u >> 16) & 1)) >> 16;
    return (unsigned short)r;
}

// ---------- fused prep: CSR + x-cast + weight transposes + wvec2 ----------
__device__ void castT_body(const float* __restrict__ W, unsigned short* __restrict__ out,
                           int K, int N, int k0, int n0, float (*t)[33], int tid) {
    int tx = tid & 31, ty = tid >> 5;
#pragma unroll
    for (int i = 0; i < 4; ++i)
        t[ty + 8 * i][tx] = W[(size_t)(k0 + ty + 8 * i) * N + n0 + tx];
    __syncthreads();
#pragma unroll
    for (int i = 0; i < 4; ++i)
        out[(size_t)(n0 + ty + 8 * i) * K + k0 + tx] = f2bf(t[tx][ty + 8 * i]);
}

__global__ __launch_bounds__(256) void k_prep(
        const float* __restrict__ x, unsigned short* __restrict__ xb,
        const float* __restrict__ W0, unsigned short* __restrict__ W0t,
        const float* __restrict__ W1, unsigned short* __restrict__ W1t,
        const float* __restrict__ W2, unsigned short* __restrict__ W2t,
        const float* __restrict__ F1, unsigned short* __restrict__ F1t,
        const float* __restrict__ F2, unsigned short* __restrict__ F2t,
        const float* __restrict__ as2, const float* __restrict__ ad2,
        float* __restrict__ WS2, float* __restrict__ WD2,
        const float* __restrict__ adj, int* __restrict__ nbr, int* __restrict__ cnt) {
    __shared__ float t[32][33];
    __shared__ int c;
    int b = blockIdx.x, tid = threadIdx.x;
    if (b < 1024) {                       // x -> bf16
        int i = b * 256 + tid;
        float4 v = ((const float4*)x)[i];
        ushort4 u; u.x = f2bf(v.x); u.y = f2bf(v.y); u.z = f2bf(v.z); u.w = f2bf(v.w);
        ((ushort4*)xb)[i] = u;
    } else if (b < 1088) {                // W0^T
        int i = b - 1024; castT_body(W0, W0t, 256, 256, (i & 7) * 32, (i >> 3) * 32, t, tid);
    } else if (b < 1152) {                // W1^T
        int i = b - 1088; castT_body(W1, W1t, 256, 256, (i & 7) * 32, (i >> 3) * 32, t, tid);
    } else if (b < 1664) {                // W2 per-head transpose
        int i = b - 1152;
        int k0 = (i & 7) * 32, d0 = ((i >> 3) & 7) * 32, h = i >> 6;
        int tx = tid & 31, ty = tid >> 5;
#pragma unroll
        for (int q = 0; q < 4; ++q)
            t[ty + 8 * q][tx] = W2[(size_t)(k0 + ty + 8 * q) * 2048 + h * 256 + d0 + tx];
        __syncthreads();
#pragma unroll
        for (int q = 0; q < 4; ++q)
            W2t[(size_t)(d0 + ty + 8 * q) * 2048 + h * 256 + k0 + tx] = f2bf(t[tx][ty + 8 * q]);
    } else if (b < 1792) {                // ff_w1^T
        int i = b - 1664; castT_body(F1, F1t, 256, 512, (i & 7) * 32, (i >> 3) * 32, t, tid);
    } else if (b < 1920) {                // ff_w2^T
        int i = b - 1792; castT_body(F2, F2t, 512, 256, (i & 15) * 32, (i >> 4) * 32, t, tid);
    } else if (b < 2432) {                // wvec2: one (h,k) output per 64-lane wave
        int id = (b - 1920) * 4 + (tid >> 6);   // 0..2047
        int h = id >> 8, k = id & 255;
        int lane = tid & 63;
        float4 w4 = *(const float4*)(W2 + (size_t)k * 2048 + h * 256 + lane * 4);
        float4 a4 = *(const float4*)(as2 + h * 256 + lane * 4);
        float4 d4 = *(const float4*)(ad2 + h * 256 + lane * 4);
        float s = w4.x * a4.x + w4.y * a4.y + w4.z * a4.z + w4.w * a4.w;
        float d = w4.x * d4.x + w4.y * d4.y + w4.z * d4.z + w4.w * d4.w;
#pragma unroll
        for (int o = 32; o; o >>= 1) { s += __shfl_xor(s, o); d += __shfl_xor(d, o); }
        if (lane == 0) { WS2[h * 256 + k] = s; WD2[h * 256 + k] = d; }
    } else {                              // CSR build (float4 scan)
        int row = b - 2432;
        if (tid == 0) c = 0;
        __syncthreads();
        float4 a4 = ((const float4*)(adj + (size_t)row * S_))[tid];
#pragma unroll
        for (int q = 0; q < 4; ++q) {
            float a = q == 0 ? a4.x : q == 1 ? a4.y : q == 2 ? a4.z : a4.w;
            if (a > 0.f) {
                int s = atomicAdd(&c, 1);
                if (s < MAXDEG) nbr[row * MAXDEG + s] = tid * 4 + q;
            }
        }
        __syncthreads();
        if (tid == 0) cnt[row] = c < MAXDEG ? c : MAXDEG;
    }
}

// ------- wide-tile split-K MFMA GEMM: tile 64M x 256N, 4 waves x (4x4 accs) -------
// K=2048 layer-2 GEMM at split-8 (Kc=256) => 512 blocks = 2 blocks/CU.
__global__ __launch_bounds__(256) void k_gemm_wide(const unsigned short* __restrict__ A,
        const unsigned short* __restrict__ Bt, float* __restrict__ P,
        int M, int N, int K, int Kc) {
    __shared__ unsigned short As[64][40];
    __shared__ unsigned short Bs[256][40];
    int tid = threadIdx.x;
    int bm = blockIdx.y * 64, bn = blockIdx.x * 256;
    int kbeg = blockIdx.z * Kc, kend = kbeg + Kc;
    int lane = tid & 63, wv = tid >> 6;
    int lrow = lane & 15, lq = lane >> 4;
    floatx4 acc[4][4] = {};
    int sm = tid >> 2, skq = (tid & 3) * 8;
    const unsigned short* Ap = A + (size_t)(bm + sm) * K + skq;
    const unsigned short* Bp0 = Bt + (size_t)(bn + sm) * K + skq;
    const unsigned short* Bp1 = Bp0 + (size_t)64 * K;
    const unsigned short* Bp2 = Bp0 + (size_t)128 * K;
    const unsigned short* Bp3 = Bp0 + (size_t)192 * K;
    short8 av  = *(const short8*)(Ap + kbeg);
    short8 bv0 = *(const short8*)(Bp0 + kbeg);
    short8 bv1 = *(const short8*)(Bp1 + kbeg);
    short8 bv2 = *(const short8*)(Bp2 + kbeg);
    short8 bv3 = *(const short8*)(Bp3 + kbeg);
    for (int k0 = kbeg; k0 < kend; k0 += 32) {
        *(short8*)&As[sm][skq]        = av;
        *(short8*)&Bs[sm][skq]        = bv0;
        *(short8*)&Bs[sm + 64][skq]   = bv1;
        *(short8*)&Bs[sm + 128][skq]  = bv2;
        *(short8*)&Bs[sm + 192][skq]  = bv3;
        __syncthreads();
        if (k0 + 32 < kend) {
            av  = *(const short8*)(Ap + k0 + 32);
            bv0 = *(const short8*)(Bp0 + k0 + 32);
            bv1 = *(const short8*)(Bp1 + k0 + 32);
            bv2 = *(const short8*)(Bp2 + k0 + 32);
            bv3 = *(const short8*)(Bp3 + k0 + 32);
        }
        short8 aF[4], bF[4];
#pragma unroll
        for (int mi = 0; mi < 4; ++mi)
            aF[mi] = *(const short8*)&As[mi * 16 + lrow][lq * 8];
#pragma unroll
        for (int ni = 0; ni < 4; ++ni)
            bF[ni] = *(const short8*)&Bs[wv * 64 + ni * 16 + lrow][lq * 8];
#pragma unroll
        for (int mi = 0; mi < 4; ++mi)
#pragma unroll
            for (int ni = 0; ni < 4; ++ni)
                acc[mi][ni] = __builtin_amdgcn_mfma_f32_16x16x32_bf16(aF[mi], bF[ni], acc[mi][ni], 0, 0, 0);
        __syncthreads();
    }
    float* out = P + (size_t)blockIdx.z * M * N;
#pragma unroll
    for (int mi = 0; mi < 4; ++mi)
#pragma unroll
        for (int ni = 0; ni < 4; ++ni)
#pragma unroll
            for (int r = 0; r < 4; ++r) {
                int grow = bm + mi * 16 + lq * 4 + r;
                int gcol = bn + wv * 64 + ni * 16 + lrow;
                out[(size_t)grow * N + gcol] = acc[mi][ni][r];
            }
}

// ------- 64x64-tile full-K GEMM, double-buffered LDS, fused bf16 out + attn scores -------
__global__ __launch_bounds__(256) void k_gemm64s(
        const unsigned short* __restrict__ A, const unsigned short* __restrict__ Bt,
        int N, int K,
        unsigned short* __restrict__ Ob,
        const float* __restrict__ p1, const float* __restrict__ p2,
        float* __restrict__ SRC, float* __restrict__ DST) {
    __shared__ unsigned short As[2][64][40];
    __shared__ unsigned short Bs[2][64][40];
    int tid = threadIdx.x;
    int bm = blockIdx.y * 64, bn = blockIdx.x * 64;
    int lane = tid & 63, wv = tid >> 6;
    int lrow = lane & 15, lq = lane >> 4;
    floatx4 acc[4] = {};
    int sm = tid >> 2, skq = (tid & 3) * 8;
    const unsigned short* Ap = A + (size_t)(bm + sm) * K + skq;
    const unsigned short* Bp = Bt + (size_t)(bn + sm) * K + skq;
    short8 av = *(const short8*)Ap;
    short8 bv = *(const short8*)Bp;
    *(short8*)&As[0][sm][skq] = av;
    *(short8*)&Bs[0][sm][skq] = bv;
    __syncthreads();
    int cur = 0;
    for (int k0 = 0; k0 < K; k0 += 32) {
        bool more = k0 + 32 < K;
        if (more) {
            av = *(const short8*)(Ap + k0 + 32);
            bv = *(const short8*)(Bp + k0 + 32);
        }
        short8 aF = *(const short8*)&As[cur][wv * 16 + lrow][lq * 8];
        short8 bF[4];
#pragma unroll
        for (int ni = 0; ni < 4; ++ni)
            bF[ni] = *(const short8*)&Bs[cur][ni * 16 + lrow][lq * 8];
#pragma unroll
        for (int ni = 0; ni < 4; ++ni)
            acc[ni] = __builtin_amdgcn_mfma_f32_16x16x32_bf16(aF, bF[ni], acc[ni], 0, 0, 0);
        if (more) {
            *(short8*)&As[cur ^ 1][sm][skq] = av;
            *(short8*)&Bs[cur ^ 1][sm][skq] = bv;
            __syncthreads();
            cur ^= 1;
        }
    }
    int row0 = bm + wv * 16 + lq * 4;
#pragma unroll
    for (int ni = 0; ni < 4; ++ni)
#pragma unroll
        for (int r = 0; r < 4; ++r)
            Ob[(size_t)(row0 + r) * N + bn + ni * 16 + lrow] = f2bf(acc[ni][r]);
    float asv[4], adv[4];
#pragma unroll
    for (int ni = 0; ni < 4; ++ni) {
        asv[ni] = p1[bn + ni * 16 + lrow];
        adv[ni] = p2[bn + ni * 16 + lrow];
    }
#pragma unroll
    for (int r = 0; r < 4; ++r) {
        float sA = acc[0][r] * asv[0] + acc[1][r] * asv[1];
        float sB = acc[2][r] * asv[2] + acc[3][r] * asv[3];
        float dA = acc[0][r] * adv[0] + acc[1][r] * adv[1];
        float dB = acc[2][r] * adv[2] + acc[3][r] * adv[3];
#pragma unroll
        for (int o = 8; o; o >>= 1) {
            sA += __shfl_xor(sA, o); sB += __shfl_xor(sB, o);
            dA += __shfl_xor(dA, o); dB += __shfl_xor(dB, o);
        }
        if (lrow == 0) {
            int h0 = bn >> 5;
            SRC[(row0 + r) * 8 + h0]     = sA;
            SRC[(row0 + r) * 8 + h0 + 1] = sB;
            DST[(row0 + r) * 8 + h0]     = dA;
            DST[(row0 + r) * 8 + h0 + 1] = dB;
        }
    }
}

// ------- attn layers 0/1: 4 rows/block, 1 wave/row, 4 dims/thread, barrier-free -------
__global__ __launch_bounds__(256) void k_attn4(const unsigned short* __restrict__ hp,
        const float* __restrict__ src, const float* __restrict__ dst,
        const int* __restrict__ nbr, const int* __restrict__ cnts,
        const float* __restrict__ X, float* __restrict__ Hout,
        unsigned short* __restrict__ Hb,
        const float* __restrict__ WS2, const float* __restrict__ WD2,
        float* __restrict__ SRC2, float* __restrict__ DST2) {
    int tid = threadIdx.x;
    int rq = tid >> 6;                    // one wave per row
    int lane = tid & 63;
    int row = blockIdx.x * 4 + rq;
    int rb = row & ~(S_ - 1);
    __shared__ int nb[4][MAXDEG];
    __shared__ float ew[4][MAXDEG * 9];
    int cnt = cnts[row];
    for (int t = lane; t < cnt; t += 64) nb[rq][t] = nbr[row * MAXDEG + t];
    float4 sa = *(const float4*)(src + row * H_);
    float4 sb = *(const float4*)(src + row * H_ + 4);
    for (int n = lane; n < cnt; n += 64) {
        int j = nb[rq][n];
        const float* dp = dst + (size_t)(rb + j) * H_;
        float4 da = *(const float4*)dp;
        float4 db = *(const float4*)(dp + 4);
        float e;
        e = sa.x + da.x; ew[rq][n * 9 + 0] = e > 0.f ? e : LRELU_ALPHA * e;
        e = sa.y + da.y; ew[rq][n * 9 + 1] = e > 0.f ? e : LRELU_ALPHA * e;
        e = sa.z + da.z; ew[rq][n * 9 + 2] = e > 0.f ? e : LRELU_ALPHA * e;
        e = sa.w + da.w; ew[rq][n * 9 + 3] = e > 0.f ? e : LRELU_ALPHA * e;
        e = sb.x + db.x; ew[rq][n * 9 + 4] = e > 0.f ? e : LRELU_ALPHA * e;
        e = sb.y + db.y; ew[rq][n * 9 + 5] = e > 0.f ? e : LRELU_ALPHA * e;
        e = sb.z + db.z; ew[rq][n * 9 + 6] = e > 0.f ? e : LRELU_ALPHA * e;
        e = sb.w + db.w; ew[rq][n * 9 + 7] = e > 0.f ? e : LRELU_ALPHA * e;
    }
    {
        int h = lane >> 3, s8 = lane & 7;
        float m = -1e30f;
        for (int n = s8; n < cnt; n += 8) m = fmaxf(m, ew[rq][n * 9 + h]);
#pragma unroll
        for (int o = 4; o; o >>= 1) m = fmaxf(m, __shfl_xor(m, o));
        float s = 0.f;
        for (int n = s8; n < cnt; n += 8) {
            float v = __expf(ew[rq][n * 9 + h] - m); ew[rq][n * 9 + h] = v; s += v;
        }
#pragma unroll
        for (int o = 4; o; o >>= 1) s += __shfl_xor(s, o);
        float inv = s > 0.f ? 1.f / s : 0.f;
        for (int n = s8; n < cnt; n += 8) ew[rq][n * 9 + h] *= inv;
    }
    int d0 = lane * 4;
    int h = lane >> 3;
    const unsigned short* hpb = hp + (size_t)rb * 256 + d0;
    const float* ewr = ew[rq];
    float A0 = 0.f, A1 = 0.f, A2 = 0.f, A3 = 0.f;
    float B0 = 0.f, B1 = 0.f, B2 = 0.f, B3 = 0.f;
    int n = 0;
    for (; n + 3 < cnt; n += 4) {
        int j0 = nb[rq][n], j1 = nb[rq][n + 1];
        int j2 = nb[rq][n + 2], j3 = nb[rq][n + 3];
        uint2 p0 = *(const uint2*)(hpb + (size_t)j0 * 256);
        uint2 p1 = *(const uint2*)(hpb + (size_t)j1 * 256);
        uint2 p2 = *(const uint2*)(hpb + (size_t)j2 * 256);
        uint2 p3 = *(const uint2*)(hpb + (size_t)j3 * 256);
        float w0 = ewr[n * 9 + h], w1 = ewr[(n + 1) * 9 + h];
        float w2 = ewr[(n + 2) * 9 + h], w3 = ewr[(n + 3) * 9 + h];
        A0 += w0 * bf2f((unsigned short)p0.x); A1 += w0 * bf2f((unsigned short)(p0.x >> 16));
        A2 += w0 * bf2f((unsigned short)p0.y); A3 += w0 * bf2f((unsigned short)(p0.y >> 16));
        B0 += w1 * bf2f((unsigned short)p1.x); B1 += w1 * bf2f((unsigned short)(p1.x >> 16));
        B2 += w1 * bf2f((unsigned short)p1.y); B3 += w1 * bf2f((unsigned short)(p1.y >> 16));
        A0 += w2 * bf2f((unsigned short)p2.x); A1 += w2 * bf2f((unsigned short)(p2.x >> 16));
        A2 += w2 * bf2f((unsigned short)p2.y); A3 += w2 * bf2f((unsigned short)(p2.y >> 16));
        B0 += w3 * bf2f((unsigned short)p3.x); B1 += w3 * bf2f((unsigned short)(p3.x >> 16));
        B2 += w3 * bf2f((unsigned short)p3.y); B3 += w3 * bf2f((unsigned short)(p3.y >> 16));
    }
    for (; n < cnt; ++n) {
        int j = nb[rq][n];
        uint2 p = *(const uint2*)(hpb + (size_t)j * 256);
        float w = ewr[n * 9 + h];
        A0 += w * bf2f((unsigned short)p.x); A1 += w * bf2f((unsigned short)(p.x >> 16));
        A2 += w * bf2f((unsigned short)p.y); A3 += w * bf2f((unsigned short)(p.y >> 16));
    }
    float4 xv = *(const float4*)(X + (size_t)row * 256 + d0);
    float ov0 = A0 + B0 + xv.x;
    float ov1 = A1 + B1 + xv.y;
    float ov2 = A2 + B2 + xv.z;
    float ov3 = A3 + B3 + xv.w;
    ov0 = ov0 > 0.f ? ov0 : (__expf(ov0) - 1.f);
    ov1 = ov1 > 0.f ? ov1 : (__expf(ov1) - 1.f);
    ov2 = ov2 > 0.f ? ov2 : (__expf(ov2) - 1.f);
    ov3 = ov3 > 0.f ? ov3 : (__expf(ov3) - 1.f);
    *(float4*)(Hout + (size_t)row * 256 + d0) = make_float4(ov0, ov1, ov2, ov3);
    ushort4 ub; ub.x = f2bf(ov0); ub.y = f2bf(ov1); ub.z = f2bf(ov2); ub.w = f2bf(ov3);
    *(ushort4*)(Hb + (size_t)row * 256 + d0) = ub;
    if (WS2 != nullptr) {
#pragma unroll
        for (int hh = 0; hh < 8; ++hh) {
            float4 wsv = *(const float4*)(WS2 + hh * 256 + d0);
            float4 wdv = *(const float4*)(WD2 + hh * 256 + d0);
            float sP = ov0 * wsv.x + ov1 * wsv.y + ov2 * wsv.z + ov3 * wsv.w;
            float dP = ov0 * wdv.x + ov1 * wdv.y + ov2 * wdv.z + ov3 * wdv.w;
#pragma unroll
            for (int o = 32; o; o >>= 1) { sP += __shfl_xor(sP, o); dP += __shfl_xor(dP, o); }
            if (lane == 0) { SRC2[row * 8 + hh] = sP; DST2[row * 8 + hh] = dP; }
        }
    }
}

// ------- layer-2 aggregation: 2 rows/block, thread = 2 dims x ALL 8 heads -------
__global__ __launch_bounds__(256) void k_attn_Y(const unsigned short* __restrict__ Hb,
        const float* __restrict__ src2, const float* __restrict__ dst2,
        const int* __restrict__ nbr, const int* __restrict__ cnts,
        unsigned short* __restrict__ Ycat) {
    int tid = threadIdx.x;
    int half = tid >> 7, sub = tid & 127;
    int row = blockIdx.x * 2 + half;
    int rb = row & ~(S_ - 1);
    __shared__ int nb[2][MAXDEG];
    __shared__ float ew[2][MAXDEG * 8];
    int cnt = cnts[row];
    for (int t = sub; t < cnt; t += 128) nb[half][t] = nbr[row * MAXDEG + t];
    float4 sa = *(const float4*)(src2 + row * H_);
    float4 sb = *(const float4*)(src2 + row * H_ + 4);
    __syncthreads();
    for (int n = sub; n < cnt; n += 128) {
        int j = nb[half][n];
        const float* dp = dst2 + (size_t)(rb + j) * H_;
        float4 da = *(const float4*)dp;
        float4 db = *(const float4*)(dp + 4);
        float e;
        e = sa.x + da.x; ew[half][n * 8 + 0] = e > 0.f ? e : LRELU_ALPHA * e;
        e = sa.y + da.y; ew[half][n * 8 + 1] = e > 0.f ? e : LRELU_ALPHA * e;
        e = sa.z + da.z; ew[half][n * 8 + 2] = e > 0.f ? e : LRELU_ALPHA * e;
        e = sa.w + da.w; ew[half][n * 8 + 3] = e > 0.f ? e : LRELU_ALPHA * e;
        e = sb.x + db.x; ew[half][n * 8 + 4] = e > 0.f ? e : LRELU_ALPHA * e;
        e = sb.y + db.y; ew[half][n * 8 + 5] = e > 0.f ? e : LRELU_ALPHA * e;
        e = sb.z + db.z; ew[half][n * 8 + 6] = e > 0.f ? e : LRELU_ALPHA * e;
        e = sb.w + db.w; ew[half][n * 8 + 7] = e > 0.f ? e : LRELU_ALPHA * e;
    }
    __syncthreads();
    {
        int h = sub >> 4, s16 = sub & 15;
        float m = -1e30f;
        for (int n = s16; n < cnt; n += 16) m = fmaxf(m, ew[half][n * 8 + h]);
#pragma unroll
        for (int o = 8; o; o >>= 1) m = fmaxf(m, __shfl_xor(m, o));
        float s = 0.f;
        for (int n = s16; n < cnt; n += 16) {
            float v = __expf(ew[half][n * 8 + h] - m); ew[half][n * 8 + h] = v; s += v;
        }
#pragma unroll
        for (int o = 8; o; o >>= 1) s += __shfl_xor(s, o);
        float inv = s > 0.f ? 0.125f / s : 0.f;
        for (int n = s16; n < cnt; n += 16) ew[half][n * 8 + h] *= inv;
    }
    __syncthreads();
    const unsigned short* hbase = Hb + (size_t)rb * 256 + 2 * sub;
    const float* ewh = ew[half];
    float aA[8] = {}, aB[8] = {};
    int n = 0;
    for (; n + 1 < cnt; n += 2) {
        int j0 = nb[half][n], j1 = nb[half][n + 1];
        unsigned int p0 = *(const unsigned int*)(hbase + (size_t)j0 * 256);
        unsigned int p1 = *(const unsigned int*)(hbase + (size_t)j1 * 256);
        float4 w0a = *(const float4*)(ewh + n * 8);
        float4 w0b = *(const float4*)(ewh + n * 8 + 4);
        float4 w1a = *(const float4*)(ewh + (n + 1) * 8);
        float4 w1b = *(const float4*)(ewh + (n + 1) * 8 + 4);
        float v0a = bf2f((unsigned short)p0), v0b = bf2f((unsigned short)(p0 >> 16));
        float v1a = bf2f((unsigned short)p1), v1b = bf2f((unsigned short)(p1 >> 16));
        aA[0] += w0a.x * v0a + w1a.x * v1a;  aB[0] += w0a.x * v0b + w1a.x * v1b;
        aA[1] += w0a.y * v0a + w1a.y * v1a;  aB[1] += w0a.y * v0b + w1a.y * v1b;
        aA[2] += w0a.z * v0a + w1a.z * v1a;  aB[2] += w0a.z * v0b + w1a.z * v1b;
        aA[3] += w0a.w * v0a + w1a.w * v1a;  aB[3] += w0a.w * v0b + w1a.w * v1b;
        aA[4] += w0b.x * v0a + w1b.x * v1a;  aB[4] += w0b.x * v0b + w1b.x * v1b;
        aA[5] += w0b.y * v0a + w1b.y * v1a;  aB[5] += w0b.y * v0b + w1b.y * v1b;
        aA[6] += w0b.z * v0a + w1b.z * v1a;  aB[6] += w0b.z * v0b + w1b.z * v1b;
        aA[7] += w0b.w * v0a + w1b.w * v1a;  aB[7] += w0b.w * v0b + w1b.w * v1b;
    }
    for (; n < cnt; ++n) {
        int j = nb[half][n];
        unsigned int p = *(const unsigned int*)(hbase + (size_t)j * 256);
        float4 wa = *(const float4*)(ewh + n * 8);
        float4 wb = *(const float4*)(ewh + n * 8 + 4);
        float va = bf2f((unsigned short)p), vb = bf2f((unsigned short)(p >> 16));
        aA[0] += wa.x * va; aB[0] += wa.x * vb;
        aA[1] += wa.y * va; aB[1] += wa.y * vb;
        aA[2] += wa.z * va; aB[2] += wa.z * vb;
        aA[3] += wa.w * va; aB[3] += wa.w * vb;
        aA[4] += wb.x * va; aB[4] += wb.x * vb;
        aA[5] += wb.y * va; aB[5] += wb.y * vb;
        aA[6] += wb.z * va; aB[6] += wb.z * vb;
        aA[7] += wb.w * va; aB[7] += wb.w * vb;
    }
    unsigned short* yb = Ycat + (size_t)row * 2048 + 2 * sub;
#pragma unroll
    for (int hh = 0; hh < 8; ++hh) {
        ushort2 u; u.x = f2bf(aA[hh]); u.y = f2bf(aB[hh]);
        *(ushort2*)(yb + hh * 256) = u;
    }
}

// ------- fused tail: split-reduce+residual+LN -> FFN1+GELU -> FFN2+residual -------
// 256 blocks x 512 threads (8 waves), 16 rows/block; activations LDS-resident.
// Row-local after PP; phase indexing reused from the round-5 megakernel (proven
// correct); LDS pitches chosen so all b128 A-fragment reads are <=2-way (free).
__global__ __launch_bounds__(512) void k_tail3(
        const float* __restrict__ PP, const float* __restrict__ Hres,
        const float* __restrict__ g, const float* __restrict__ bta,
        const unsigned short* __restrict__ F1t, const float* __restrict__ b1,
        const unsigned short* __restrict__ F2t, const float* __restrict__ b2,
        float* __restrict__ out) {
    __shared__ unsigned short alnb[16][264];  // LN out bf16, pitch 264 (132dw = 4 mod 32)
    __shared__ float hln[16][260];            // LN out fp32, pitch 260 (= 4 mod 32)
    __shared__ unsigned short mid[16][520];   // GELU out bf16, pitch 520 (260dw)
    __shared__ unsigned short Bs[256][40];    // B staging (proven pitch)
    int tid = threadIdx.x;
    int lane = tid & 63, wv = tid >> 6;
    int lrow = lane & 15, lq = lane >> 4;
    int r0 = blockIdx.x * 16;

    // ---- Phase A: reduce 8 PP splits + residual + LayerNorm (one row per wave-pass)
    float4 gg = ((const float4*)g)[lane];
    float4 bbv = ((const float4*)bta)[lane];
#pragma unroll
    for (int pass = 0; pass < 2; ++pass) {
        int lr = wv * 2 + pass;               // local row 0..15
        int row = r0 + lr;
        float4 v = ((const float4*)(Hres + (size_t)row * 256))[lane];
#pragma unroll
        for (int sp = 0; sp < 8; ++sp) {
            float4 p = ((const float4*)(PP + (size_t)sp * 1048576 + (size_t)row * 256))[lane];
            v.x += p.x; v.y += p.y; v.z += p.z; v.w += p.w;
        }
        float s = v.x + v.y + v.z + v.w;
        float q = v.x * v.x + v.y * v.y + v.z * v.z + v.w * v.w;
#pragma unroll
        for (int o = 32; o; o >>= 1) { s += __shfl_xor(s, o); q += __shfl_xor(q, o); }
        float mu = s * (1.f / 256.f);
        float var = q * (1.f / 256.f) - mu * mu;
        if (var < 0.f) var = 0.f;
        float rs = rsqrtf(var + 1e-5f);
        float4 o4;
        o4.x = (v.x - mu) * rs * gg.x + bbv.x;
        o4.y = (v.y - mu) * rs * gg.y + bbv.y;
        o4.z = (v.z - mu) * rs * gg.z + bbv.z;
        o4.w = (v.w - mu) * rs * gg.w + bbv.w;
        *(float4*)&hln[lr][lane * 4] = o4;
        ushort4 ub; ub.x = f2bf(o4.x); ub.y = f2bf(o4.y); ub.z = f2bf(o4.z); ub.w = f2bf(o4.w);
        *(ushort4*)&alnb[lr][lane * 4] = ub;
    }
    __syncthreads();

    // ---- Phase B: FFN1 (K=256) in two 256-col halves + bias + GELU -> mid
    int sm = tid >> 1, skq = (tid & 1) * 16;  // B-staging: 2 threads/row, 32B each
    int colb = wv * 32 + lrow;
#pragma unroll 1
    for (int hf = 0; hf < 2; ++hf) {
        floatx4 acc1[2] = {};
        const unsigned short* Fp = F1t + (size_t)(hf * 256 + sm) * 256 + skq;
        for (int st = 0; st < 8; ++st) {
            int k0 = st * 32;
            *(short8*)&Bs[sm][skq]     = *(const short8*)(Fp + k0);
            *(short8*)&Bs[sm][skq + 8] = *(const short8*)(Fp + k0 + 8);
            __syncthreads();
            short8 aF  = *(const short8*)&alnb[lrow][k0 + lq * 8];
            short8 bF0 = *(const short8*)&Bs[wv * 32 + lrow][lq * 8];
            short8 bF1 = *(const short8*)&Bs[wv * 32 + 16 + lrow][lq * 8];
            acc1[0] = __builtin_amdgcn_mfma_f32_16x16x32_bf16(aF, bF0, acc1[0], 0, 0, 0);
            acc1[1] = __builtin_amdgcn_mfma_f32_16x16x32_bf16(aF, bF1, acc1[1], 0, 0, 0);
            __syncthreads();
        }
#pragma unroll
        for (int ni = 0; ni < 2; ++ni) {
            int gcol = hf * 256 + colb + ni * 16;
            float bb = b1[gcol];
#pragma unroll
            for (int r = 0; r < 4; ++r) {
                float xx = acc1[ni][r] + bb;
                float tt = tanhf(0.7978845608028654f * (xx + 0.044715f * xx * xx * xx));
                mid[lq * 4 + r][gcol] = f2bf(0.5f * xx * (1.f + tt));
            }
        }
    }
    __syncthreads();   // mid complete (and Bs free) before Phase C

    // ---- Phase C: FFN2 (K=512) + bias + residual(hln) -> out
    floatx4 acc2[2] = {};
    const unsigned short* F2p = F2t + (size_t)sm * 512 + skq;
    for (int st = 0; st < 16; ++st) {
        int k0 = st * 32;
        *(short8*)&Bs[sm][skq]     = *(const short8*)(F2p + k0);
        *(short8*)&Bs[sm][skq + 8] = *(const short8*)(F2p + k0 + 8);
        __syncthreads();
        short8 aF  = *(const short8*)&mid[lrow][k0 + lq * 8];
        short8 bF0 = *(const short8*)&Bs[wv * 32 + lrow][lq * 8];
        short8 bF1 = *(const short8*)&Bs[wv * 32 + 16 + lrow][lq * 8];
        acc2[0] = __builtin_amdgcn_mfma_f32_16x16x32_bf16(aF, bF0, acc2[0], 0, 0, 0);
        acc2[1] = __builtin_amdgcn_mfma_f32_16x16x32_bf16(aF, bF1, acc2[1], 0, 0, 0);
        __syncthreads();
    }
#pragma unroll
    for (int ni = 0; ni < 2; ++ni) {
        int col = colb + ni * 16;
        float bb = b2[col];
#pragma unroll
        for (int r = 0; r < 4; ++r) {
            int lr = lq * 4 + r;
            out[(size_t)(r0 + lr) * 256 + col] = acc2[ni][r] + bb + hln[lr][col];
        }
    }
}

extern "C" void kernel_launch(void* const* d_in, const int* in_sizes, int n_in,
                              void* d_out, int out_size, void* d_ws, size_t ws_size,
                              hipStream_t stream) {
    const float* adj   = (const float*)d_in[0];
    const float* x     = (const float*)d_in[1];
    const float* W0    = (const float*)d_in[2];
    const float* as0   = (const float*)d_in[3];
    const float* ad0   = (const float*)d_in[4];
    const float* W1    = (const float*)d_in[5];
    const float* as1   = (const float*)d_in[6];
    const float* ad1   = (const float*)d_in[7];
    const float* W2    = (const float*)d_in[8];
    const float* as2   = (const float*)d_in[9];
    const float* ad2   = (const float*)d_in[10];
    const float* ln_g  = (const float*)d_in[11];
    const float* ln_b  = (const float*)d_in[12];
    const float* ff_w1 = (const float*)d_in[13];
    const float* ff_b1 = (const float*)d_in[14];
    const float* ff_w2 = (const float*)d_in[15];
    const float* ff_b2 = (const float*)d_in[16];

    float* ws = (float*)d_ws;
    float* H    = ws;                          // [4096,256] f32
    unsigned short* Ycat = (unsigned short*)(ws + 2097152);   // [4096,2048] bf16
    unsigned short* HPb  = (unsigned short*)(ws + 6291456);   // [4096,256] bf16
    unsigned short* xb   = (unsigned short*)(ws + 6815744);
    unsigned short* Hb   = (unsigned short*)(ws + 7340032);
    unsigned short* W0t  = (unsigned short*)(ws + 9437184);   // [256,256]
    unsigned short* W1t  = (unsigned short*)(ws + 9469952);
    unsigned short* W2t  = (unsigned short*)(ws + 9502720);   // [256,2048]
    unsigned short* F1t  = (unsigned short*)(ws + 9764864);   // [512,256]
    unsigned short* F2t  = (unsigned short*)(ws + 9830400);   // [256,512]
    float* WS2  = ws + 9895936;                // [8,256]
    float* WD2  = ws + 9897984;                // [8,256]
    float* SRC  = ws + 9900032;                // [4096,8]
    float* DST  = ws + 9932800;
    float* SRC2 = ws + 9965568;                // [4096,8] layer-2 scores
    float* DST2 = ws + 9998336;
    int*   NBR  = (int*)(ws + 10031104);       // [4096,128]
    int*   CNT  = (int*)(ws + 10555392);       // [4096]
    float* PP   = ws + 12582912;               // split-K partials [8][4096][256] f32

    // one prep kernel: CSR + casts + transposes + wvec2
    k_prep<<<6528, 256, 0, stream>>>(x, xb, W0, W0t, W1, W1t, W2, W2t,
                                     ff_w1, F1t, ff_w2, F2t, as2, ad2, WS2, WD2,
                                     adj, NBR, CNT);

    // ---- GAT layer 0: full-K GEMM with fused bf16-cast + scores ----
    k_gemm64s<<<dim3(4, 64), 256, 0, stream>>>(xb, W0t, 256, 256, HPb, as0, ad0, SRC, DST);
    k_attn4<<<1024, 256, 0, stream>>>(HPb, SRC, DST, NBR, CNT, x, H, Hb,
                                      nullptr, nullptr, nullptr, nullptr);

    // ---- GAT layer 1 (layer-2 scores fused into attn epilogue) ----
    k_gemm64s<<<dim3(4, 64), 256, 0, stream>>>(Hb, W1t, 256, 256, HPb, as1, ad1, SRC, DST);
    k_attn4<<<1024, 256, 0, stream>>>(HPb, SRC, DST, NBR, CNT, H, H, Hb,
                                      WS2, WD2, SRC2, DST2);

    // ---- GAT layer 2: aggregate H, split-8 GEMM with W2 ----
    k_attn_Y<<<2048, 256, 0, stream>>>(Hb, SRC2, DST2, NBR, CNT, Ycat);
    k_gemm_wide<<<dim3(1, 64, 8), 256, 0, stream>>>(Ycat, W2t, PP, 4096, 256, 2048, 256);

    // ---- fused tail: LN-reduce + FFN1 + FFN2 (row-local, LDS-resident) ----
    k_tail3<<<256, 512, 0, stream>>>(PP, H, ln_g, ln_b, F1t, ff_b1, F2t, ff_b2,
                                     (float*)d_out);
}

// Round 10
// 209.456 us; speedup vs baseline: 1.0123x; 1.0123x over previous
//
#include <hip/hip_runtime.h>
#include <hip/hip_bf16.h>

#define B_ 4
#define S_ 1024
#define D_ 256
#define H_ 8
#define LRELU_ALPHA 0.2f
#define MAXDEG 128

typedef __attribute__((ext_vector_type(8))) short short8;
typedef __attribute__((ext_vector_type(4))) float floatx4;

__device__ __forceinline__ float bf2f(unsigned short u) {
    union { unsigned int i; float f; } c; c.i = ((unsigned int)u) << 16; return c.f;
}
__device__ __forceinline__ unsigned short f2bf(float f) {
    union { float f; unsigned int u; } c; c.f = f;
    unsigned int r = (c.u + 0x7FFF + ((c.u >> 16) & 1)) >> 16;
    return (unsigned short)r;
}

// ---------- fused prep: CSR + x-cast + weight transposes + wvec2 ----------
__device__ void castT_body(const float* __restrict__ W, unsigned short* __restrict__ out,
                           int K, int N, int k0, int n0, float (*t)[33], int tid) {
    int tx = tid & 31, ty = tid >> 5;
#pragma unroll
    for (int i = 0; i < 4; ++i)
        t[ty + 8 * i][tx] = W[(size_t)(k0 + ty + 8 * i) * N + n0 + tx];
    __syncthreads();
#pragma unroll
    for (int i = 0; i < 4; ++i)
        out[(size_t)(n0 + ty + 8 * i) * K + k0 + tx] = f2bf(t[tx][ty + 8 * i]);
}

__global__ __launch_bounds__(256) void k_prep(
        const float* __restrict__ x, unsigned short* __restrict__ xb,
        const float* __restrict__ W0, unsigned short* __restrict__ W0t,
        const float* __restrict__ W1, unsigned short* __restrict__ W1t,
        const float* __restrict__ W2, unsigned short* __restrict__ W2t,
        const float* __restrict__ F1, unsigned short* __restrict__ F1t,
        const float* __restrict__ F2, unsigned short* __restrict__ F2t,
        const float* __restrict__ as2, const float* __restrict__ ad2,
        float* __restrict__ WS2, float* __restrict__ WD2,
        const float* __restrict__ adj, int* __restrict__ nbr, int* __restrict__ cnt) {
    __shared__ float t[32][33];
    __shared__ int c;
    int b = blockIdx.x, tid = threadIdx.x;
    if (b < 1024) {                       // x -> bf16
        int i = b * 256 + tid;
        float4 v = ((const float4*)x)[i];
        ushort4 u; u.x = f2bf(v.x); u.y = f2bf(v.y); u.z = f2bf(v.z); u.w = f2bf(v.w);
        ((ushort4*)xb)[i] = u;
    } else if (b < 1088) {                // W0^T
        int i = b - 1024; castT_body(W0, W0t, 256, 256, (i & 7) * 32, (i >> 3) * 32, t, tid);
    } else if (b < 1152) {                // W1^T
        int i = b - 1088; castT_body(W1, W1t, 256, 256, (i & 7) * 32, (i >> 3) * 32, t, tid);
    } else if (b < 1664) {                // W2 per-head transpose
        int i = b - 1152;
        int k0 = (i & 7) * 32, d0 = ((i >> 3) & 7) * 32, h = i >> 6;
        int tx = tid & 31, ty = tid >> 5;
#pragma unroll
        for (int q = 0; q < 4; ++q)
            t[ty + 8 * q][tx] = W2[(size_t)(k0 + ty + 8 * q) * 2048 + h * 256 + d0 + tx];
        __syncthreads();
#pragma unroll
        for (int q = 0; q < 4; ++q)
            W2t[(size_t)(d0 + ty + 8 * q) * 2048 + h * 256 + k0 + tx] = f2bf(t[tx][ty + 8 * q]);
    } else if (b < 1792) {                // ff_w1^T
        int i = b - 1664; castT_body(F1, F1t, 256, 512, (i & 7) * 32, (i >> 3) * 32, t, tid);
    } else if (b < 1920) {                // ff_w2^T
        int i = b - 1792; castT_body(F2, F2t, 512, 256, (i & 15) * 32, (i >> 4) * 32, t, tid);
    } else if (b < 2432) {                // wvec2: one (h,k) output per 64-lane wave
        int id = (b - 1920) * 4 + (tid >> 6);   // 0..2047
        int h = id >> 8, k = id & 255;
        int lane = tid & 63;
        float4 w4 = *(const float4*)(W2 + (size_t)k * 2048 + h * 256 + lane * 4);
        float4 a4 = *(const float4*)(as2 + h * 256 + lane * 4);
        float4 d4 = *(const float4*)(ad2 + h * 256 + lane * 4);
        float s = w4.x * a4.x + w4.y * a4.y + w4.z * a4.z + w4.w * a4.w;
        float d = w4.x * d4.x + w4.y * d4.y + w4.z * d4.z + w4.w * d4.w;
#pragma unroll
        for (int o = 32; o; o >>= 1) { s += __shfl_xor(s, o); d += __shfl_xor(d, o); }
        if (lane == 0) { WS2[h * 256 + k] = s; WD2[h * 256 + k] = d; }
    } else {                              // CSR build (float4 scan)
        int row = b - 2432;
        if (tid == 0) c = 0;
        __syncthreads();
        float4 a4 = ((const float4*)(adj + (size_t)row * S_))[tid];
#pragma unroll
        for (int q = 0; q < 4; ++q) {
            float a = q == 0 ? a4.x : q == 1 ? a4.y : q == 2 ? a4.z : a4.w;
            if (a > 0.f) {
                int s = atomicAdd(&c, 1);
                if (s < MAXDEG) nbr[row * MAXDEG + s] = tid * 4 + q;
            }
        }
        __syncthreads();
        if (tid == 0) cnt[row] = c < MAXDEG ? c : MAXDEG;
    }
}

// ------- wide-tile split-K MFMA GEMM: tile 64M x 256N, 4 waves x (4x4 accs) -------
// K=2048 layer-2 GEMM at split-8 (Kc=256) => 512 blocks = 2 blocks/CU.
__global__ __launch_bounds__(256) void k_gemm_wide(const unsigned short* __restrict__ A,
        const unsigned short* __restrict__ Bt, float* __restrict__ P,
        int M, int N, int K, int Kc) {
    __shared__ unsigned short As[64][40];
    __shared__ unsigned short Bs[256][40];
    int tid = threadIdx.x;
    int bm = blockIdx.y * 64, bn = blockIdx.x * 256;
    int kbeg = blockIdx.z * Kc, kend = kbeg + Kc;
    int lane = tid & 63, wv = tid >> 6;
    int lrow = lane & 15, lq = lane >> 4;
    floatx4 acc[4][4] = {};
    int sm = tid >> 2, skq = (tid & 3) * 8;
    const unsigned short* Ap = A + (size_t)(bm + sm) * K + skq;
    const unsigned short* Bp0 = Bt + (size_t)(bn + sm) * K + skq;
    const unsigned short* Bp1 = Bp0 + (size_t)64 * K;
    const unsigned short* Bp2 = Bp0 + (size_t)128 * K;
    const unsigned short* Bp3 = Bp0 + (size_t)192 * K;
    short8 av  = *(const short8*)(Ap + kbeg);
    short8 bv0 = *(const short8*)(Bp0 + kbeg);
    short8 bv1 = *(const short8*)(Bp1 + kbeg);
    short8 bv2 = *(const short8*)(Bp2 + kbeg);
    short8 bv3 = *(const short8*)(Bp3 + kbeg);
    for (int k0 = kbeg; k0 < kend; k0 += 32) {
        *(short8*)&As[sm][skq]        = av;
        *(short8*)&Bs[sm][skq]        = bv0;
        *(short8*)&Bs[sm + 64][skq]   = bv1;
        *(short8*)&Bs[sm + 128][skq]  = bv2;
        *(short8*)&Bs[sm + 192][skq]  = bv3;
        __syncthreads();
        if (k0 + 32 < kend) {
            av  = *(const short8*)(Ap + k0 + 32);
            bv0 = *(const short8*)(Bp0 + k0 + 32);
            bv1 = *(const short8*)(Bp1 + k0 + 32);
            bv2 = *(const short8*)(Bp2 + k0 + 32);
            bv3 = *(const short8*)(Bp3 + k0 + 32);
        }
        short8 aF[4], bF[4];
#pragma unroll
        for (int mi = 0; mi < 4; ++mi)
            aF[mi] = *(const short8*)&As[mi * 16 + lrow][lq * 8];
#pragma unroll
        for (int ni = 0; ni < 4; ++ni)
            bF[ni] = *(const short8*)&Bs[wv * 64 + ni * 16 + lrow][lq * 8];
#pragma unroll
        for (int mi = 0; mi < 4; ++mi)
#pragma unroll
            for (int ni = 0; ni < 4; ++ni)
                acc[mi][ni] = __builtin_amdgcn_mfma_f32_16x16x32_bf16(aF[mi], bF[ni], acc[mi][ni], 0, 0, 0);
        __syncthreads();
    }
    float* out = P + (size_t)blockIdx.z * M * N;
#pragma unroll
    for (int mi = 0; mi < 4; ++mi)
#pragma unroll
        for (int ni = 0; ni < 4; ++ni)
#pragma unroll
            for (int r = 0; r < 4; ++r) {
                int grow = bm + mi * 16 + lq * 4 + r;
                int gcol = bn + wv * 64 + ni * 16 + lrow;
                out[(size_t)grow * N + gcol] = acc[mi][ni][r];
            }
}

// ------- 64x64-tile full-K GEMM, double-buffered LDS, fused bf16 out + attn scores -------
__global__ __launch_bounds__(256) void k_gemm64s(
        const unsigned short* __restrict__ A, const unsigned short* __restrict__ Bt,
        int N, int K,
        unsigned short* __restrict__ Ob,
        const float* __restrict__ p1, const float* __restrict__ p2,
        float* __restrict__ SRC, float* __restrict__ DST) {
    __shared__ unsigned short As[2][64][40];
    __shared__ unsigned short Bs[2][64][40];
    int tid = threadIdx.x;
    int bm = blockIdx.y * 64, bn = blockIdx.x * 64;
    int lane = tid & 63, wv = tid >> 6;
    int lrow = lane & 15, lq = lane >> 4;
    floatx4 acc[4] = {};
    int sm = tid >> 2, skq = (tid & 3) * 8;
    const unsigned short* Ap = A + (size_t)(bm + sm) * K + skq;
    const unsigned short* Bp = Bt + (size_t)(bn + sm) * K + skq;
    short8 av = *(const short8*)Ap;
    short8 bv = *(const short8*)Bp;
    *(short8*)&As[0][sm][skq] = av;
    *(short8*)&Bs[0][sm][skq] = bv;
    __syncthreads();
    int cur = 0;
    for (int k0 = 0; k0 < K; k0 += 32) {
        bool more = k0 + 32 < K;
        if (more) {
            av = *(const short8*)(Ap + k0 + 32);
            bv = *(const short8*)(Bp + k0 + 32);
        }
        short8 aF = *(const short8*)&As[cur][wv * 16 + lrow][lq * 8];
        short8 bF[4];
#pragma unroll
        for (int ni = 0; ni < 4; ++ni)
            bF[ni] = *(const short8*)&Bs[cur][ni * 16 + lrow][lq * 8];
#pragma unroll
        for (int ni = 0; ni < 4; ++ni)
            acc[ni] = __builtin_amdgcn_mfma_f32_16x16x32_bf16(aF, bF[ni], acc[ni], 0, 0, 0);
        if (more) {
            *(short8*)&As[cur ^ 1][sm][skq] = av;
            *(short8*)&Bs[cur ^ 1][sm][skq] = bv;
            __syncthreads();
            cur ^= 1;
        }
    }
    int row0 = bm + wv * 16 + lq * 4;
#pragma unroll
    for (int ni = 0; ni < 4; ++ni)
#pragma unroll
        for (int r = 0; r < 4; ++r)
            Ob[(size_t)(row0 + r) * N + bn + ni * 16 + lrow] = f2bf(acc[ni][r]);
    float asv[4], adv[4];
#pragma unroll
    for (int ni = 0; ni < 4; ++ni) {
        asv[ni] = p1[bn + ni * 16 + lrow];
        adv[ni] = p2[bn + ni * 16 + lrow];
    }
#pragma unroll
    for (int r = 0; r < 4; ++r) {
        float sA = acc[0][r] * asv[0] + acc[1][r] * asv[1];
        float sB = acc[2][r] * asv[2] + acc[3][r] * asv[3];
        float dA = acc[0][r] * adv[0] + acc[1][r] * adv[1];
        float dB = acc[2][r] * adv[2] + acc[3][r] * adv[3];
#pragma unroll
        for (int o = 8; o; o >>= 1) {
            sA += __shfl_xor(sA, o); sB += __shfl_xor(sB, o);
            dA += __shfl_xor(dA, o); dB += __shfl_xor(dB, o);
        }
        if (lrow == 0) {
            int h0 = bn >> 5;
            SRC[(row0 + r) * 8 + h0]     = sA;
            SRC[(row0 + r) * 8 + h0 + 1] = sB;
            DST[(row0 + r) * 8 + h0]     = dA;
            DST[(row0 + r) * 8 + h0 + 1] = dB;
        }
    }
}

// ------- attn layers 0/1: 4 rows/block, 1 wave/row, 4 dims/thread, barrier-free -------
__global__ __launch_bounds__(256) void k_attn4(const unsigned short* __restrict__ hp,
        const float* __restrict__ src, const float* __restrict__ dst,
        const int* __restrict__ nbr, const int* __restrict__ cnts,
        const float* __restrict__ X, float* __restrict__ Hout,
        unsigned short* __restrict__ Hb,
        const float* __restrict__ WS2, const float* __restrict__ WD2,
        float* __restrict__ SRC2, float* __restrict__ DST2) {
    int tid = threadIdx.x;
    int rq = tid >> 6;                    // one wave per row
    int lane = tid & 63;
    int row = blockIdx.x * 4 + rq;
    int rb = row & ~(S_ - 1);
    __shared__ int nb[4][MAXDEG];
    __shared__ float ew[4][MAXDEG * 9];
    int cnt = cnts[row];
    for (int t = lane; t < cnt; t += 64) nb[rq][t] = nbr[row * MAXDEG + t];
    float4 sa = *(const float4*)(src + row * H_);
    float4 sb = *(const float4*)(src + row * H_ + 4);
    for (int n = lane; n < cnt; n += 64) {
        int j = nb[rq][n];
        const float* dp = dst + (size_t)(rb + j) * H_;
        float4 da = *(const float4*)dp;
        float4 db = *(const float4*)(dp + 4);
        float e;
        e = sa.x + da.x; ew[rq][n * 9 + 0] = e > 0.f ? e : LRELU_ALPHA * e;
        e = sa.y + da.y; ew[rq][n * 9 + 1] = e > 0.f ? e : LRELU_ALPHA * e;
        e = sa.z + da.z; ew[rq][n * 9 + 2] = e > 0.f ? e : LRELU_ALPHA * e;
        e = sa.w + da.w; ew[rq][n * 9 + 3] = e > 0.f ? e : LRELU_ALPHA * e;
        e = sb.x + db.x; ew[rq][n * 9 + 4] = e > 0.f ? e : LRELU_ALPHA * e;
        e = sb.y + db.y; ew[rq][n * 9 + 5] = e > 0.f ? e : LRELU_ALPHA * e;
        e = sb.z + db.z; ew[rq][n * 9 + 6] = e > 0.f ? e : LRELU_ALPHA * e;
        e = sb.w + db.w; ew[rq][n * 9 + 7] = e > 0.f ? e : LRELU_ALPHA * e;
    }
    {
        int h = lane >> 3, s8 = lane & 7;
        float m = -1e30f;
        for (int n = s8; n < cnt; n += 8) m = fmaxf(m, ew[rq][n * 9 + h]);
#pragma unroll
        for (int o = 4; o; o >>= 1) m = fmaxf(m, __shfl_xor(m, o));
        float s = 0.f;
        for (int n = s8; n < cnt; n += 8) {
            float v = __expf(ew[rq][n * 9 + h] - m); ew[rq][n * 9 + h] = v; s += v;
        }
#pragma unroll
        for (int o = 4; o; o >>= 1) s += __shfl_xor(s, o);
        float inv = s > 0.f ? 1.f / s : 0.f;
        for (int n = s8; n < cnt; n += 8) ew[rq][n * 9 + h] *= inv;
    }
    int d0 = lane * 4;
    int h = lane >> 3;
    const unsigned short* hpb = hp + (size_t)rb * 256 + d0;
    const float* ewr = ew[rq];
    float A0 = 0.f, A1 = 0.f, A2 = 0.f, A3 = 0.f;
    float B0 = 0.f, B1 = 0.f, B2 = 0.f, B3 = 0.f;
    int n = 0;
    for (; n + 3 < cnt; n += 4) {
        int j0 = nb[rq][n], j1 = nb[rq][n + 1];
        int j2 = nb[rq][n + 2], j3 = nb[rq][n + 3];
        uint2 p0 = *(const uint2*)(hpb + (size_t)j0 * 256);
        uint2 p1 = *(const uint2*)(hpb + (size_t)j1 * 256);
        uint2 p2 = *(const uint2*)(hpb + (size_t)j2 * 256);
        uint2 p3 = *(const uint2*)(hpb + (size_t)j3 * 256);
        float w0 = ewr[n * 9 + h], w1 = ewr[(n + 1) * 9 + h];
        float w2 = ewr[(n + 2) * 9 + h], w3 = ewr[(n + 3) * 9 + h];
        A0 += w0 * bf2f((unsigned short)p0.x); A1 += w0 * bf2f((unsigned short)(p0.x >> 16));
        A2 += w0 * bf2f((unsigned short)p0.y); A3 += w0 * bf2f((unsigned short)(p0.y >> 16));
        B0 += w1 * bf2f((unsigned short)p1.x); B1 += w1 * bf2f((unsigned short)(p1.x >> 16));
        B2 += w1 * bf2f((unsigned short)p1.y); B3 += w1 * bf2f((unsigned short)(p1.y >> 16));
        A0 += w2 * bf2f((unsigned short)p2.x); A1 += w2 * bf2f((unsigned short)(p2.x >> 16));
        A2 += w2 * bf2f((unsigned short)p2.y); A3 += w2 * bf2f((unsigned short)(p2.y >> 16));
        B0 += w3 * bf2f((unsigned short)p3.x); B1 += w3 * bf2f((unsigned short)(p3.x >> 16));
        B2 += w3 * bf2f((unsigned short)p3.y); B3 += w3 * bf2f((unsigned short)(p3.y >> 16));
    }
    for (; n < cnt; ++n) {
        int j = nb[rq][n];
        uint2 p = *(const uint2*)(hpb + (size_t)j * 256);
        float w = ewr[n * 9 + h];
        A0 += w * bf2f((unsigned short)p.x); A1 += w * bf2f((unsigned short)(p.x >> 16));
        A2 += w * bf2f((unsigned short)p.y); A3 += w * bf2f((unsigned short)(p.y >> 16));
    }
    float4 xv = *(const float4*)(X + (size_t)row * 256 + d0);
    float ov0 = A0 + B0 + xv.x;
    float ov1 = A1 + B1 + xv.y;
    float ov2 = A2 + B2 + xv.z;
    float ov3 = A3 + B3 + xv.w;
    ov0 = ov0 > 0.f ? ov0 : (__expf(ov0) - 1.f);
    ov1 = ov1 > 0.f ? ov1 : (__expf(ov1) - 1.f);
    ov2 = ov2 > 0.f ? ov2 : (__expf(ov2) - 1.f);
    ov3 = ov3 > 0.f ? ov3 : (__expf(ov3) - 1.f);
    *(float4*)(Hout + (size_t)row * 256 + d0) = make_float4(ov0, ov1, ov2, ov3);
    ushort4 ub; ub.x = f2bf(ov0); ub.y = f2bf(ov1); ub.z = f2bf(ov2); ub.w = f2bf(ov3);
    *(ushort4*)(Hb + (size_t)row * 256 + d0) = ub;
    if (WS2 != nullptr) {
#pragma unroll
        for (int hh = 0; hh < 8; ++hh) {
            float4 wsv = *(const float4*)(WS2 + hh * 256 + d0);
            float4 wdv = *(const float4*)(WD2 + hh * 256 + d0);
            float sP = ov0 * wsv.x + ov1 * wsv.y + ov2 * wsv.z + ov3 * wsv.w;
            float dP = ov0 * wdv.x + ov1 * wdv.y + ov2 * wdv.z + ov3 * wdv.w;
#pragma unroll
            for (int o = 32; o; o >>= 1) { sP += __shfl_xor(sP, o); dP += __shfl_xor(dP, o); }
            if (lane == 0) { SRC2[row * 8 + hh] = sP; DST2[row * 8 + hh] = dP; }
        }
    }
}

// ------- layer-2 aggregation: 2 rows/block, thread = 2 dims x ALL 8 heads -------
__global__ __launch_bounds__(256) void k_attn_Y(const unsigned short* __restrict__ Hb,
        const float* __restrict__ src2, const float* __restrict__ dst2,
        const int* __restrict__ nbr, const int* __restrict__ cnts,
        unsigned short* __restrict__ Ycat) {
    int tid = threadIdx.x;
    int half = tid >> 7, sub = tid & 127;
    int row = blockIdx.x * 2 + half;
    int rb = row & ~(S_ - 1);
    __shared__ int nb[2][MAXDEG];
    __shared__ float ew[2][MAXDEG * 8];
    int cnt = cnts[row];
    for (int t = sub; t < cnt; t += 128) nb[half][t] = nbr[row * MAXDEG + t];
    float4 sa = *(const float4*)(src2 + row * H_);
    float4 sb = *(const float4*)(src2 + row * H_ + 4);
    __syncthreads();
    for (int n = sub; n < cnt; n += 128) {
        int j = nb[half][n];
        const float* dp = dst2 + (size_t)(rb + j) * H_;
        float4 da = *(const float4*)dp;
        float4 db = *(const float4*)(dp + 4);
        float e;
        e = sa.x + da.x; ew[half][n * 8 + 0] = e > 0.f ? e : LRELU_ALPHA * e;
        e = sa.y + da.y; ew[half][n * 8 + 1] = e > 0.f ? e : LRELU_ALPHA * e;
        e = sa.z + da.z; ew[half][n * 8 + 2] = e > 0.f ? e : LRELU_ALPHA * e;
        e = sa.w + da.w; ew[half][n * 8 + 3] = e > 0.f ? e : LRELU_ALPHA * e;
        e = sb.x + db.x; ew[half][n * 8 + 4] = e > 0.f ? e : LRELU_ALPHA * e;
        e = sb.y + db.y; ew[half][n * 8 + 5] = e > 0.f ? e : LRELU_ALPHA * e;
        e = sb.z + db.z; ew[half][n * 8 + 6] = e > 0.f ? e : LRELU_ALPHA * e;
        e = sb.w + db.w; ew[half][n * 8 + 7] = e > 0.f ? e : LRELU_ALPHA * e;
    }
    __syncthreads();
    {
        int h = sub >> 4, s16 = sub & 15;
        float m = -1e30f;
        for (int n = s16; n < cnt; n += 16) m = fmaxf(m, ew[half][n * 8 + h]);
#pragma unroll
        for (int o = 8; o; o >>= 1) m = fmaxf(m, __shfl_xor(m, o));
        float s = 0.f;
        for (int n = s16; n < cnt; n += 16) {
            float v = __expf(ew[half][n * 8 + h] - m); ew[half][n * 8 + h] = v; s += v;
        }
#pragma unroll
        for (int o = 8; o; o >>= 1) s += __shfl_xor(s, o);
        float inv = s > 0.f ? 0.125f / s : 0.f;
        for (int n = s16; n < cnt; n += 16) ew[half][n * 8 + h] *= inv;
    }
    __syncthreads();
    const unsigned short* hbase = Hb + (size_t)rb * 256 + 2 * sub;
    const float* ewh = ew[half];
    float aA[8] = {}, aB[8] = {};
    int n = 0;
    for (; n + 1 < cnt; n += 2) {
        int j0 = nb[half][n], j1 = nb[half][n + 1];
        unsigned int p0 = *(const unsigned int*)(hbase + (size_t)j0 * 256);
        unsigned int p1 = *(const unsigned int*)(hbase + (size_t)j1 * 256);
        float4 w0a = *(const float4*)(ewh + n * 8);
        float4 w0b = *(const float4*)(ewh + n * 8 + 4);
        float4 w1a = *(const float4*)(ewh + (n + 1) * 8);
        float4 w1b = *(const float4*)(ewh + (n + 1) * 8 + 4);
        float v0a = bf2f((unsigned short)p0), v0b = bf2f((unsigned short)(p0 >> 16));
        float v1a = bf2f((unsigned short)p1), v1b = bf2f((unsigned short)(p1 >> 16));
        aA[0] += w0a.x * v0a + w1a.x * v1a;  aB[0] += w0a.x * v0b + w1a.x * v1b;
        aA[1] += w0a.y * v0a + w1a.y * v1a;  aB[1] += w0a.y * v0b + w1a.y * v1b;
        aA[2] += w0a.z * v0a + w1a.z * v1a;  aB[2] += w0a.z * v0b + w1a.z * v1b;
        aA[3] += w0a.w * v0a + w1a.w * v1a;  aB[3] += w0a.w * v0b + w1a.w * v1b;
        aA[4] += w0b.x * v0a + w1b.x * v1a;  aB[4] += w0b.x * v0b + w1b.x * v1b;
        aA[5] += w0b.y * v0a + w1b.y * v1a;  aB[5] += w0b.y * v0b + w1b.y * v1b;
        aA[6] += w0b.z * v0a + w1b.z * v1a;  aB[6] += w0b.z * v0b + w1b.z * v1b;
        aA[7] += w0b.w * v0a + w1b.w * v1a;  aB[7] += w0b.w * v0b + w1b.w * v1b;
    }
    for (; n < cnt; ++n) {
        int j = nb[half][n];
        unsigned int p = *(const unsigned int*)(hbase + (size_t)j * 256);
        float4 wa = *(const float4*)(ewh + n * 8);
        float4 wb = *(const float4*)(ewh + n * 8 + 4);
        float va = bf2f((unsigned short)p), vb = bf2f((unsigned short)(p >> 16));
        aA[0] += wa.x * va; aB[0] += wa.x * vb;
        aA[1] += wa.y * va; aB[1] += wa.y * vb;
        aA[2] += wa.z * va; aB[2] += wa.z * vb;
        aA[3] += wa.w * va; aB[3] += wa.w * vb;
        aA[4] += wb.x * va; aB[4] += wb.x * vb;
        aA[5] += wb.y * va; aB[5] += wb.y * vb;
        aA[6] += wb.z * va; aB[6] += wb.z * vb;
        aA[7] += wb.w * va; aB[7] += wb.w * vb;
    }
    unsigned short* yb = Ycat + (size_t)row * 2048 + 2 * sub;
#pragma unroll
    for (int hh = 0; hh < 8; ++hh) {
        ushort2 u; u.x = f2bf(aA[hh]); u.y = f2bf(aB[hh]);
        *(ushort2*)(yb + hh * 256) = u;
    }
}

// ------- fused tail v2: split-reduce+residual+LN -> FFN1+GELU -> FFN2+residual -------
// 256 blocks x 512 threads, 16 rows/block. Double-buffered B staging (1 barrier/K-step),
// register prefetch. Bs pitch 36 shorts (18 dw): 18*r mod 32 distinct for r<16 =>
// conflict-free b128 fragment reads. Final residual taken from bf16 LN (alnb).
__global__ __launch_bounds__(512) void k_tail3(
        const float* __restrict__ PP, const float* __restrict__ Hres,
        const float* __restrict__ g, const float* __restrict__ bta,
        const unsigned short* __restrict__ F1t, const float* __restrict__ b1,
        const unsigned short* __restrict__ F2t, const float* __restrict__ b2,
        float* __restrict__ out) {
    __shared__ unsigned short alnb[16][264];  // LN out bf16, pitch 264
    __shared__ unsigned short mid[16][520];   // GELU out bf16, pitch 520
    __shared__ unsigned short Bs[2][256][36]; // dbuf B staging, pitch 36
    int tid = threadIdx.x;
    int lane = tid & 63, wv = tid >> 6;
    int lrow = lane & 15, lq = lane >> 4;
    int r0 = blockIdx.x * 16;

    // ---- Phase A: reduce 8 PP splits + residual + LayerNorm -> alnb (bf16)
    float4 gg = ((const float4*)g)[lane];
    float4 bbv = ((const float4*)bta)[lane];
#pragma unroll
    for (int pass = 0; pass < 2; ++pass) {
        int lr = wv * 2 + pass;               // local row 0..15
        int row = r0 + lr;
        float4 v = ((const float4*)(Hres + (size_t)row * 256))[lane];
#pragma unroll
        for (int sp = 0; sp < 8; ++sp) {
            float4 p = ((const float4*)(PP + (size_t)sp * 1048576 + (size_t)row * 256))[lane];
            v.x += p.x; v.y += p.y; v.z += p.z; v.w += p.w;
        }
        float s = v.x + v.y + v.z + v.w;
        float q = v.x * v.x + v.y * v.y + v.z * v.z + v.w * v.w;
#pragma unroll
        for (int o = 32; o; o >>= 1) { s += __shfl_xor(s, o); q += __shfl_xor(q, o); }
        float mu = s * (1.f / 256.f);
        float var = q * (1.f / 256.f) - mu * mu;
        if (var < 0.f) var = 0.f;
        float rs = rsqrtf(var + 1e-5f);
        ushort4 ub;
        ub.x = f2bf((v.x - mu) * rs * gg.x + bbv.x);
        ub.y = f2bf((v.y - mu) * rs * gg.y + bbv.y);
        ub.z = f2bf((v.z - mu) * rs * gg.z + bbv.z);
        ub.w = f2bf((v.w - mu) * rs * gg.w + bbv.w);
        *(ushort4*)&alnb[lr][lane * 4] = ub;
    }
    __syncthreads();

    int sm = tid >> 1, skq = (tid & 1) * 16;  // B-staging: 2 threads/row, 32B each
    int colb = wv * 32 + lrow;

    // ---- Phase B: FFN1 (K=256) in two 256-col halves + bias + GELU -> mid
#pragma unroll 1
    for (int hf = 0; hf < 2; ++hf) {
        floatx4 acc1[2] = {};
        const unsigned short* Fp = F1t + (size_t)(hf * 256 + sm) * 256 + skq;
        short8 rb0 = *(const short8*)Fp;
        short8 rb1 = *(const short8*)(Fp + 8);
        __syncthreads();                      // prior consumers of Bs done
        *(short8*)&Bs[0][sm][skq]     = rb0;
        *(short8*)&Bs[0][sm][skq + 8] = rb1;
        __syncthreads();
        int cur = 0;
        for (int st = 0; st < 8; ++st) {
            bool more = st < 7;
            if (more) {
                rb0 = *(const short8*)(Fp + (st + 1) * 32);
                rb1 = *(const short8*)(Fp + (st + 1) * 32 + 8);
            }
            int k0 = st * 32;
            short8 aF  = *(const short8*)&alnb[lrow][k0 + lq * 8];
            short8 bF0 = *(const short8*)&Bs[cur][wv * 32 + lrow][lq * 8];
            short8 bF1 = *(const short8*)&Bs[cur][wv * 32 + 16 + lrow][lq * 8];
            acc1[0] = __builtin_amdgcn_mfma_f32_16x16x32_bf16(aF, bF0, acc1[0], 0, 0, 0);
            acc1[1] = __builtin_amdgcn_mfma_f32_16x16x32_bf16(aF, bF1, acc1[1], 0, 0, 0);
            if (more) {
                *(short8*)&Bs[cur ^ 1][sm][skq]     = rb0;
                *(short8*)&Bs[cur ^ 1][sm][skq + 8] = rb1;
                __syncthreads();
                cur ^= 1;
            }
        }
#pragma unroll
        for (int ni = 0; ni < 2; ++ni) {
            int gcol = hf * 256 + colb + ni * 16;
            float bb = b1[gcol];
#pragma unroll
            for (int r = 0; r < 4; ++r) {
                float xx = acc1[ni][r] + bb;
                float tt = tanhf(0.7978845608028654f * (xx + 0.044715f * xx * xx * xx));
                mid[lq * 4 + r][gcol] = f2bf(0.5f * xx * (1.f + tt));
            }
        }
    }
    __syncthreads();   // mid complete + Bs free before Phase C

    // ---- Phase C: FFN2 (K=512) + bias + residual(alnb) -> out
    floatx4 acc2[2] = {};
    const unsigned short* F2p = F2t + (size_t)sm * 512 + skq;
    short8 rc0 = *(const short8*)F2p;
    short8 rc1 = *(const short8*)(F2p + 8);
    *(short8*)&Bs[0][sm][skq]     = rc0;
    *(short8*)&Bs[0][sm][skq + 8] = rc1;
    __syncthreads();
    int cur = 0;
    for (int st = 0; st < 16; ++st) {
        bool more = st < 15;
        if (more) {
            rc0 = *(const short8*)(F2p + (st + 1) * 32);
            rc1 = *(const short8*)(F2p + (st + 1) * 32 + 8);
        }
        int k0 = st * 32;
        short8 aF  = *(const short8*)&mid[lrow][k0 + lq * 8];
        short8 bF0 = *(const short8*)&Bs[cur][wv * 32 + lrow][lq * 8];
        short8 bF1 = *(const short8*)&Bs[cur][wv * 32 + 16 + lrow][lq * 8];
        acc2[0] = __builtin_amdgcn_mfma_f32_16x16x32_bf16(aF, bF0, acc2[0], 0, 0, 0);
        acc2[1] = __builtin_amdgcn_mfma_f32_16x16x32_bf16(aF, bF1, acc2[1], 0, 0, 0);
        if (more) {
            *(short8*)&Bs[cur ^ 1][sm][skq]     = rc0;
            *(short8*)&Bs[cur ^ 1][sm][skq + 8] = rc1;
            __syncthreads();
            cur ^= 1;
        }
    }
#pragma unroll
    for (int ni = 0; ni < 2; ++ni) {
        int col = colb + ni * 16;
        float bb = b2[col];
#pragma unroll
        for (int r = 0; r < 4; ++r) {
            int lr = lq * 4 + r;
            float res = bf2f(alnb[lr][col]);
            out[(size_t)(r0 + lr) * 256 + col] = acc2[ni][r] + bb + res;
        }
    }
}

extern "C" void kernel_launch(void* const* d_in, const int* in_sizes, int n_in,
                              void* d_out, int out_size, void* d_ws, size_t ws_size,
                              hipStream_t stream) {
    const float* adj   = (const float*)d_in[0];
    const float* x     = (const float*)d_in[1];
    const float* W0    = (const float*)d_in[2];
    const float* as0   = (const float*)d_in[3];
    const float* ad0   = (const float*)d_in[4];
    const float* W1    = (const float*)d_in[5];
    const float* as1   = (const float*)d_in[6];
    const float* ad1   = (const float*)d_in[7];
    const float* W2    = (const float*)d_in[8];
    const float* as2   = (const float*)d_in[9];
    const float* ad2   = (const float*)d_in[10];
    const float* ln_g  = (const float*)d_in[11];
    const float* ln_b  = (const float*)d_in[12];
    const float* ff_w1 = (const float*)d_in[13];
    const float* ff_b1 = (const float*)d_in[14];
    const float* ff_w2 = (const float*)d_in[15];
    const float* ff_b2 = (const float*)d_in[16];

    float* ws = (float*)d_ws;
    float* H    = ws;                          // [4096,256] f32
    unsigned short* Ycat = (unsigned short*)(ws + 2097152);   // [4096,2048] bf16
    unsigned short* HPb  = (unsigned short*)(ws + 6291456);   // [4096,256] bf16
    unsigned short* xb   = (unsigned short*)(ws + 6815744);
    unsigned short* Hb   = (unsigned short*)(ws + 7340032);
    unsigned short* W0t  = (unsigned short*)(ws + 9437184);   // [256,256]
    unsigned short* W1t  = (unsigned short*)(ws + 9469952);
    unsigned short* W2t  = (unsigned short*)(ws + 9502720);   // [256,2048]
    unsigned short* F1t  = (unsigned short*)(ws + 9764864);   // [512,256]
    unsigned short* F2t  = (unsigned short*)(ws + 9830400);   // [256,512]
    float* WS2  = ws + 9895936;                // [8,256]
    float* WD2  = ws + 9897984;                // [8,256]
    float* SRC  = ws + 9900032;                // [4096,8]
    float* DST  = ws + 9932800;
    float* SRC2 = ws + 9965568;                // [4096,8] layer-2 scores
    float* DST2 = ws + 9998336;
    int*   NBR  = (int*)(ws + 10031104);       // [4096,128]
    int*   CNT  = (int*)(ws + 10555392);       // [4096]
    float* PP   = ws + 12582912;               // split-K partials [8][4096][256] f32

    // one prep kernel: CSR + casts + transposes + wvec2
    k_prep<<<6528, 256, 0, stream>>>(x, xb, W0, W0t, W1, W1t, W2, W2t,
                                     ff_w1, F1t, ff_w2, F2t, as2, ad2, WS2, WD2,
                                     adj, NBR, CNT);

    // ---- GAT layer 0: full-K GEMM with fused bf16-cast + scores ----
    k_gemm64s<<<dim3(4, 64), 256, 0, stream>>>(xb, W0t, 256, 256, HPb, as0, ad0, SRC, DST);
    k_attn4<<<1024, 256, 0, stream>>>(HPb, SRC, DST, NBR, CNT, x, H, Hb,
                                      nullptr, nullptr, nullptr, nullptr);

    // ---- GAT layer 1 (layer-2 scores fused into attn epilogue) ----
    k_gemm64s<<<dim3(4, 64), 256, 0, stream>>>(Hb, W1t, 256, 256, HPb, as1, ad1, SRC, DST);
    k_attn4<<<1024, 256, 0, stream>>>(HPb, SRC, DST, NBR, CNT, H, H, Hb,
                                      WS2, WD2, SRC2, DST2);

    // ---- GAT layer 2: aggregate H, split-8 GEMM with W2 ----
    k_attn_Y<<<2048, 256, 0, stream>>>(Hb, SRC2, DST2, NBR, CNT, Ycat);
    k_gemm_wide<<<dim3(1, 64, 8), 256, 0, stream>>>(Ycat, W2t, PP, 4096, 256, 2048, 256);

    // ---- fused tail v2: LN-reduce + FFN1 + FFN2, dbuf staging ----
    k_tail3<<<256, 512, 0, stream>>>(PP, H, ln_g, ln_b, F1t, ff_b1, F2t, ff_b2,
                                     (float*)d_out);
}